// Round 1
// baseline (1442.699 us; speedup 1.0000x reference)
//
#include <hip/hip_runtime.h>

// Dims (fixed for this problem)
constexpr int HI = 256, WI = 256;   // reg_feat spatial
constexpr int HO = 512, WO = 512;   // upsampled spatial
constexpr int CI = 32;              // feat channels
constexpr int CK = 49;              // 7x7 unfold channels

// ---------------------------------------------------------------------------
// Stage A: ConvTranspose2d(32,32,4,stride=2,padding=1)
// x:[32][256][256], wt:[in=32][out=32][4][4], bt:[32] -> f0:[32][512][512]
// y[o,oh,ow] = bt[o] + sum_i sum_{kh,kw} x[i,(oh+1-kh)/2,(ow+1-kw)/2]*wt[i,o,kh,kw]
//   where (oh+1-kh) and (ow+1-kw) must be even and indices in range.
// Each thread: 2 pixels (ow0=tid, ow0+256 — same parity), all 32 out channels.
// ---------------------------------------------------------------------------
__global__ __launch_bounds__(256, 2)
void kA(const float* __restrict__ x, const float* __restrict__ wt,
        const float* __restrict__ bt, float* __restrict__ f0)
{
    __shared__ float wl[16 * 1024];  // [tap=kh*4+kw][i][o], 64 KiB
    const int tid = threadIdx.x;
    // coalesced float4 read of wt, permuted scatter into LDS
    for (int j = tid; j < 4096; j += 256) {
        const int r = j >> 2, tq = j & 3;       // r = i*32+o
        const float4 v = reinterpret_cast<const float4*>(wt)[j];
        wl[(4 * tq + 0) * 1024 + r] = v.x;
        wl[(4 * tq + 1) * 1024 + r] = v.y;
        wl[(4 * tq + 2) * 1024 + r] = v.z;
        wl[(4 * tq + 3) * 1024 + r] = v.w;
    }
    __syncthreads();

    const int oh  = blockIdx.x;
    const int kh0 = (oh & 1) ? 0 : 1;
    const int ow0 = tid;                 // second pixel at ow0+256 (same parity)
    const int kw0 = (ow0 & 1) ? 0 : 1;

    float acc0[32], acc1[32];
    #pragma unroll
    for (int o = 0; o < 32; ++o) { acc0[o] = 0.f; acc1[o] = 0.f; }

    for (int i = 0; i < CI; ++i) {
        const float* xi = x + i * (HI * WI);
        #pragma unroll
        for (int a = 0; a < 2; ++a) {
            const int kh = kh0 + 2 * a;
            const int ih = (oh + 1 - kh) >> 1;
            const bool vh = ((unsigned)ih < (unsigned)HI);
            const float* xr = xi + ih * WI;
            #pragma unroll
            for (int d = 0; d < 2; ++d) {
                const int kw  = kw0 + 2 * d;
                const int iw0 = (ow0 + 1 - kw) >> 1;
                const int iw1 = iw0 + 128;
                const float xv0 = (vh && (unsigned)iw0 < (unsigned)WI) ? xr[iw0] : 0.f;
                const float xv1 = (vh && (unsigned)iw1 < (unsigned)WI) ? xr[iw1] : 0.f;
                const float* wp = wl + (kh * 4 + kw) * 1024 + i * 32;
                #pragma unroll
                for (int o = 0; o < 32; ++o) {
                    const float wv = wp[o];
                    acc0[o] += xv0 * wv;
                    acc1[o] += xv1 * wv;
                }
            }
        }
    }
    #pragma unroll
    for (int o = 0; o < 32; ++o) {
        const float bv = bt[o];
        f0[(o * HO + oh) * WO + ow0]       = acc0[o] + bv;
        f0[(o * HO + oh) * WO + ow0 + 256] = acc1[o] + bv;
    }
}

// ---------------------------------------------------------------------------
// Stage B: conv 7x1 (vertical), pad H by 3. f0:[32][512][512], w1:[49][32][7],
// b1:[49] -> f1:[49][512][512]
// Wave = 64 columns; thread: 2 rows (sliding window), all 49 out channels.
// ---------------------------------------------------------------------------
__global__ __launch_bounds__(256, 2)
void kB(const float* __restrict__ f0, const float* __restrict__ w1,
        const float* __restrict__ b1, float* __restrict__ f1)
{
    __shared__ float wl[32 * 7 * 52];    // [i][t][o padded to 52] 46.6 KiB
    const int tid = threadIdx.x;
    for (int j = tid; j < CK * CI * 7; j += 256) {   // j = (o*32+i)*7+t (coalesced src)
        const int o = j / 224, r = j % 224;
        const int i = r / 7, t = r % 7;
        wl[(i * 7 + t) * 52 + o] = w1[j];
    }
    __syncthreads();

    const int lane = tid & 63;
    const int wv_  = tid >> 6;
    const int c    = ((blockIdx.x & 7) << 6) + lane;
    const int h0   = ((blockIdx.x >> 3) << 3) + wv_ * 2;

    float acc0[CK], acc1[CK];
    #pragma unroll
    for (int o = 0; o < CK; ++o) { acc0[o] = 0.f; acc1[o] = 0.f; }

    for (int i = 0; i < CI; ++i) {
        const float* xi = f0 + i * (HO * WO) + c;
        float xw[9];
        #pragma unroll
        for (int k = 0; k < 9; ++k) {
            const int hh = h0 + k - 3;
            xw[k] = ((unsigned)hh < (unsigned)HO) ? xi[hh * WO] : 0.f;
        }
        const float* wli = wl + i * (7 * 52);
        #pragma unroll
        for (int t = 0; t < 7; ++t) {
            const float* wrow = wli + t * 52;
            #pragma unroll
            for (int o = 0; o < CK; ++o) {
                const float wv = wrow[o];
                acc0[o] += wv * xw[t];
                acc1[o] += wv * xw[t + 1];
            }
        }
    }
    #pragma unroll
    for (int o = 0; o < CK; ++o) {
        const float bv = b1[o];
        f1[(o * HO + h0) * WO + c]     = acc0[o] + bv;
        f1[(o * HO + h0 + 1) * WO + c] = acc1[o] + bv;
    }
}

// ---------------------------------------------------------------------------
// Stage C: conv 1x7 (horizontal, pad W by 3) + softmax over 49 + unfold-weighted
// flow average. f1:[49][512][512], w2:[49][49][7], b2:[49],
// flow:[2][512][512] -> out:[2][512][512]
// Block = one row; thread: 2 adjacent columns (wa=2*tid, wa+1).
// Weights staged in 2 i-chunks (25+24) to keep LDS at 36.4 KiB.
// ---------------------------------------------------------------------------
__global__ __launch_bounds__(256, 2)
void kC(const float* __restrict__ f1, const float* __restrict__ w2,
        const float* __restrict__ b2, const float* __restrict__ flow,
        float* __restrict__ out)
{
    __shared__ float wl[25 * 7 * 52];    // chunk [li][t][o padded 52]
    const int tid = threadIdx.x;
    const int h  = blockIdx.x;
    const int wa = tid * 2;

    float s0[CK], s1[CK];
    #pragma unroll
    for (int o = 0; o < CK; ++o) { s0[o] = 0.f; s1[o] = 0.f; }

    for (int chunk = 0; chunk < 2; ++chunk) {
        const int i0 = chunk ? 25 : 0;
        const int ni = chunk ? 24 : 25;
        const int nq = ni * 7;
        __syncthreads();                               // wl reuse barrier
        for (int j = tid; j < CK * nq; j += 256) {
            const int o = j / nq, q = j % nq;          // q = li*7+t
            wl[q * 52 + o] = w2[o * 343 + i0 * 7 + q]; // coalesced within o-runs
        }
        __syncthreads();
        for (int li = 0; li < ni; ++li) {
            const int i = i0 + li;
            const float* xi = f1 + ((size_t)i * HO + h) * WO;
            float xw[10];
            #pragma unroll
            for (int k = 0; k < 10; ++k) {
                const int ww = wa + k - 3;
                xw[k] = ((unsigned)ww < (unsigned)WO) ? xi[ww] : 0.f;
            }
            const float* wli = wl + li * (7 * 52);
            #pragma unroll
            for (int t = 0; t < 7; ++t) {
                const float* wrow = wli + t * 52;
                #pragma unroll
                for (int o = 0; o < CK; ++o) {
                    const float wv = wrow[o];
                    s0[o] += wv * xw[t];
                    s1[o] += wv * xw[t + 1];
                }
            }
        }
    }

    // epilogue: f2 = s + b2; sq = f2^2; dist = exp(min(sq)-sq); weighted flow avg
    #pragma unroll
    for (int o = 0; o < CK; ++o) {
        const float b = b2[o];
        const float v0 = s0[o] + b; s0[o] = v0 * v0;
        const float v1 = s1[o] + b; s1[o] = v1 * v1;
    }
    float m0 = s0[0], m1 = s1[0];
    #pragma unroll
    for (int o = 1; o < CK; ++o) { m0 = fminf(m0, s0[o]); m1 = fminf(m1, s1[o]); }

    const float* fx = flow;
    const float* fy = flow + HO * WO;
    float div0 = 0.f, sx0 = 0.f, sy0 = 0.f;
    float div1 = 0.f, sx1 = 0.f, sy1 = 0.f;
    #pragma unroll
    for (int ki = 0; ki < 7; ++ki) {
        const int hh = h + ki - 3;
        const bool vh = ((unsigned)hh < (unsigned)HO);
        const float* fxr = fx + hh * WO;
        const float* fyr = fy + hh * WO;
        #pragma unroll
        for (int kj = 0; kj < 7; ++kj) {
            const int o   = ki * 7 + kj;
            const int w0c = wa + kj - 3;
            const int w1c = w0c + 1;
            const float d0 = __expf(m0 - s0[o]);
            const float d1 = __expf(m1 - s1[o]);
            div0 += d0; div1 += d1;
            const bool v0 = vh && ((unsigned)w0c < (unsigned)WO);
            const bool v1 = vh && ((unsigned)w1c < (unsigned)WO);
            sx0 += d0 * (v0 ? fxr[w0c] : 0.f);
            sy0 += d0 * (v0 ? fyr[w0c] : 0.f);
            sx1 += d1 * (v1 ? fxr[w1c] : 0.f);
            sy1 += d1 * (v1 ? fyr[w1c] : 0.f);
        }
    }
    out[h * WO + wa]                = sx0 / div0;
    out[h * WO + wa + 1]            = sx1 / div1;
    out[HO * WO + h * WO + wa]      = sy0 / div0;
    out[HO * WO + h * WO + wa + 1]  = sy1 / div1;
}

// ---------------------------------------------------------------------------
extern "C" void kernel_launch(void* const* d_in, const int* in_sizes, int n_in,
                              void* d_out, int out_size, void* d_ws, size_t ws_size,
                              hipStream_t stream) {
    const float* reg_feat = (const float*)d_in[0];
    const float* flow     = (const float*)d_in[1];
    const float* wt       = (const float*)d_in[2];
    const float* bt       = (const float*)d_in[3];
    const float* w1       = (const float*)d_in[4];
    const float* b1       = (const float*)d_in[5];
    const float* w2       = (const float*)d_in[6];
    const float* b2       = (const float*)d_in[7];
    float* out = (float*)d_out;
    (void)in_sizes; (void)n_in; (void)out_size; (void)ws_size;

    // per-batch intermediates in workspace: f0 (32*512*512 f32) + f1 (49*512*512 f32)
    float* f0 = (float*)d_ws;
    float* f1 = f0 + (size_t)CI * HO * WO;

    for (int b = 0; b < 4; ++b) {
        const float* xb  = reg_feat + (size_t)b * CI * HI * WI;
        const float* flb = flow     + (size_t)b * 2 * HO * WO;
        float*       ob  = out      + (size_t)b * 2 * HO * WO;
        kA<<<512, 256, 0, stream>>>(xb, wt, bt, f0);
        kB<<<512, 256, 0, stream>>>(f0, w1, b1, f1);
        kC<<<512, 256, 0, stream>>>(f1, w2, b2, flb, ob);
    }
}